// Round 1
// baseline (798.937 us; speedup 1.0000x reference)
//
#include <hip/hip_runtime.h>

#define D_DIM 1024
#define F_DIM 4096
#define E_NUM 16
#define T_NUM 2048

#define BM 128
#define BN 128
#define BK 64

typedef __bf16 bf16x8 __attribute__((ext_vector_type(8)));
typedef float f32x4 __attribute__((ext_vector_type(4)));

// round-to-nearest f32 -> bf16 pair packed into u32 (lo = a, hi = b)
__device__ __forceinline__ unsigned pack2bf(float a, float b) {
  unsigned ua = __builtin_bit_cast(unsigned, a);
  unsigned ub = __builtin_bit_cast(unsigned, b);
  return ((ub + 0x8000u) & 0xffff0000u) | ((ua + 0x8000u) >> 16);
}
__device__ __forceinline__ unsigned short f2bf(float a) {
  unsigned ua = __builtin_bit_cast(unsigned, a);
  return (unsigned short)((ua + 0x8000u) >> 16);
}

// ---------------- router: logits (f32, exact enough for stable top-2) + top2 + softmax
__global__ __launch_bounds__(256) void moe_router(
    const float* __restrict__ x, const float* __restrict__ gate,
    float* __restrict__ logits_out, int* __restrict__ topi, float* __restrict__ topw)
{
  __shared__ float lg[16][17];
  int tid = threadIdx.x;
  int tbase = blockIdx.x * 16;
  int tt = tid >> 4, e = tid & 15;
  const float4* xr = (const float4*)(x + (size_t)(tbase + tt) * D_DIM);
  const float4* gw = (const float4*)(gate + (size_t)e * D_DIM);
  float acc = 0.f;
  #pragma unroll 4
  for (int k = 0; k < D_DIM / 4; ++k) {
    float4 a = xr[k], b = gw[k];
    acc += a.x * b.x + a.y * b.y + a.z * b.z + a.w * b.w;
  }
  lg[tt][e] = acc;
  logits_out[(size_t)(tbase + tt) * E_NUM + e] = acc;
  __syncthreads();
  if (tid < 16) {
    int t = tid;
    float best = -1e30f; int i0 = 0;
    #pragma unroll
    for (int j = 0; j < 16; ++j) { float v = lg[t][j]; if (v > best) { best = v; i0 = j; } }
    float best1 = -1e30f; int i1 = 0;
    #pragma unroll
    for (int j = 0; j < 16; ++j) { if (j == i0) continue; float v = lg[t][j]; if (v > best1) { best1 = v; i1 = j; } }
    float e1 = __expf(best1 - best);          // <= 1
    float inv = 1.f / (1.f + e1);
    int gt = tbase + t;
    topi[gt * 2]     = i0;  topi[gt * 2 + 1] = i1;
    topw[gt * 2]     = inv; topw[gt * 2 + 1] = e1 * inv;
  }
}

// ---------------- deterministic routing: per-expert compacted row lists (wave e owns expert e)
__global__ __launch_bounds__(1024) void moe_route_build(
    const int* __restrict__ topi,
    int* __restrict__ cnt, int* __restrict__ rowbase,
    int* __restrict__ rowlist, int* __restrict__ rowpos)
{
  __shared__ int scnt[16];
  __shared__ int sbase[17];
  int wave = threadIdx.x >> 6;
  int lane = threadIdx.x & 63;
  int total = 0;
  for (int c = 0; c < (T_NUM * 2) / 64; ++c) {
    int s = c * 64 + lane;
    unsigned long long m = __ballot(topi[s] == wave);
    total += __popcll(m);
  }
  if (lane == 0) scnt[wave] = total;
  __syncthreads();
  if (threadIdx.x == 0) {
    int acc = 0;
    for (int e2 = 0; e2 < 16; ++e2) { sbase[e2] = acc; cnt[e2] = scnt[e2]; acc += scnt[e2]; }
    sbase[16] = acc;
    for (int e2 = 0; e2 <= 16; ++e2) rowbase[e2] = sbase[e2];
  }
  __syncthreads();
  int running = sbase[wave];
  for (int c = 0; c < (T_NUM * 2) / 64; ++c) {
    int s = c * 64 + lane;
    int ei = topi[s];
    unsigned long long m = __ballot(ei == wave);
    if (ei == wave) {
      int pos = running + __popcll(m & ((1ull << lane) - 1ull));
      rowlist[pos] = s;          // slot id: token = s>>1
      rowpos[s] = pos;
    }
    running += __popcll(m);
  }
}

// ---------------- GEMM1: H[row][f] = silu(x@w1^T) * (x@w3^T), bf16 MFMA, dual-B fused
__global__ __launch_bounds__(256, 2) void moe_gemm1(
    const float* __restrict__ x, const float* __restrict__ w1s, const float* __restrict__ w3s,
    const int* __restrict__ cnt, const int* __restrict__ rowbase, const int* __restrict__ rowlist,
    unsigned short* __restrict__ H)
{
  int e = blockIdx.z, mt = blockIdx.y, nt = blockIdx.x;
  int Ne = cnt[e];
  if (mt * BM >= Ne) return;
  int rbase = rowbase[e];

  __shared__ unsigned short Xs[BM * BK];
  __shared__ unsigned short W1s[BN * BK];
  __shared__ unsigned short W3s[BN * BK];
  __shared__ int toks[BM];

  int tid = threadIdx.x;
  if (tid < BM) {
    int lr = mt * BM + tid;
    toks[tid] = (lr < Ne) ? (rowlist[rbase + lr] >> 1) : -1;
  }

  const float* w1e = w1s + (size_t)e * F_DIM * D_DIM + (size_t)(nt * BN) * D_DIM;
  const float* w3e = w3s + (size_t)e * F_DIM * D_DIM + (size_t)(nt * BN) * D_DIM;

  f32x4 acc1[4][4], acc3[4][4];
  #pragma unroll
  for (int i = 0; i < 4; ++i)
    #pragma unroll
    for (int j = 0; j < 4; ++j) {
      acc1[i][j] = {0.f, 0.f, 0.f, 0.f};
      acc3[i][j] = {0.f, 0.f, 0.f, 0.f};
    }

  int lane = tid & 63;
  int wid = tid >> 6;
  int wm = wid >> 1, wn = wid & 1;
  int lr16 = lane & 15, lq = lane >> 4;

  __syncthreads();   // toks visible

  for (int ks = 0; ks < D_DIM / BK; ++ks) {
    int kb = ks * BK;
    // stage X tile (gathered rows, f32 -> bf16, XOR-swizzled LDS)
    #pragma unroll
    for (int it = 0; it < 8; ++it) {
      int idx = it * 256 + tid;
      int row = idx >> 4, c4 = idx & 15;
      int tok = toks[row];
      float4 v = make_float4(0.f, 0.f, 0.f, 0.f);
      if (tok >= 0) v = *(const float4*)(x + (size_t)tok * D_DIM + kb + c4 * 4);
      unsigned bo = (unsigned)(row * (BK * 2) + c4 * 8) ^ ((row & 7) << 4);
      *(uint2*)((char*)Xs + bo) = make_uint2(pack2bf(v.x, v.y), pack2bf(v.z, v.w));
    }
    // stage W1/W3 tiles
    #pragma unroll
    for (int it = 0; it < 8; ++it) {
      int idx = it * 256 + tid;
      int row = idx >> 4, c4 = idx & 15;
      size_t goff = (size_t)row * D_DIM + kb + c4 * 4;
      float4 v = *(const float4*)(w1e + goff);
      float4 u = *(const float4*)(w3e + goff);
      unsigned bo = (unsigned)(row * (BK * 2) + c4 * 8) ^ ((row & 7) << 4);
      *(uint2*)((char*)W1s + bo) = make_uint2(pack2bf(v.x, v.y), pack2bf(v.z, v.w));
      *(uint2*)((char*)W3s + bo) = make_uint2(pack2bf(u.x, u.y), pack2bf(u.z, u.w));
    }
    __syncthreads();
    #pragma unroll
    for (int ksub = 0; ksub < 2; ++ksub) {
      int colb = (ksub * 32 + lq * 8) * 2;
      bf16x8 af[4];
      #pragma unroll
      for (int mi = 0; mi < 4; ++mi) {
        int row = wm * 64 + mi * 16 + lr16;
        unsigned bo = (unsigned)(row * (BK * 2) + colb) ^ ((row & 7) << 4);
        af[mi] = *(const bf16x8*)((const char*)Xs + bo);
      }
      #pragma unroll
      for (int ni = 0; ni < 4; ++ni) {
        int row = wn * 64 + ni * 16 + lr16;
        unsigned bo = (unsigned)(row * (BK * 2) + colb) ^ ((row & 7) << 4);
        bf16x8 b1 = *(const bf16x8*)((const char*)W1s + bo);
        bf16x8 b3 = *(const bf16x8*)((const char*)W3s + bo);
        #pragma unroll
        for (int mi = 0; mi < 4; ++mi) {
          acc1[mi][ni] = __builtin_amdgcn_mfma_f32_16x16x32_bf16(af[mi], b1, acc1[mi][ni], 0, 0, 0);
          acc3[mi][ni] = __builtin_amdgcn_mfma_f32_16x16x32_bf16(af[mi], b3, acc3[mi][ni], 0, 0, 0);
        }
      }
    }
    __syncthreads();
  }
  // epilogue: silu(a1)*a3 -> H (bf16), guarded rows
  #pragma unroll
  for (int mi = 0; mi < 4; ++mi) {
    int mb = wm * 64 + mi * 16 + lq * 4;
    #pragma unroll
    for (int r = 0; r < 4; ++r) {
      int lrow = mt * BM + mb + r;
      if (lrow < Ne) {
        size_t hrow = (size_t)(rbase + lrow) * F_DIM;
        #pragma unroll
        for (int ni = 0; ni < 4; ++ni) {
          int f = nt * BN + wn * 64 + ni * 16 + lr16;
          float a1v = acc1[mi][ni][r];
          float a3v = acc3[mi][ni][r];
          float hv = (a1v / (1.f + __expf(-a1v))) * a3v;
          H[hrow + f] = f2bf(hv);
        }
      }
    }
  }
}

// ---------------- GEMM2: Y[row][d] = H @ w2^T (unscaled), f32 out
__global__ __launch_bounds__(256, 2) void moe_gemm2(
    const unsigned short* __restrict__ H, const float* __restrict__ w2s,
    const int* __restrict__ cnt, const int* __restrict__ rowbase,
    float* __restrict__ Y)
{
  int e = blockIdx.z, mt = blockIdx.y, nt = blockIdx.x;
  int Ne = cnt[e];
  if (mt * BM >= Ne) return;
  int rbase = rowbase[e];

  __shared__ unsigned short As[BM * BK];
  __shared__ unsigned short Bs[BN * BK];

  int tid = threadIdx.x;
  const float* w2e = w2s + (size_t)e * D_DIM * F_DIM + (size_t)(nt * BN) * F_DIM;

  f32x4 acc[4][4];
  #pragma unroll
  for (int i = 0; i < 4; ++i)
    #pragma unroll
    for (int j = 0; j < 4; ++j) acc[i][j] = {0.f, 0.f, 0.f, 0.f};

  int lane = tid & 63, wid = tid >> 6;
  int wm = wid >> 1, wn = wid & 1;
  int lr16 = lane & 15, lq = lane >> 4;

  for (int ks = 0; ks < F_DIM / BK; ++ks) {
    int kb = ks * BK;
    // stage A from H (already bf16), zero-fill invalid rows
    #pragma unroll
    for (int it = 0; it < 4; ++it) {
      int idx = it * 256 + tid;
      int row = idx >> 3, c8 = idx & 7;
      int lrow = mt * BM + row;
      uint4 v = make_uint4(0, 0, 0, 0);
      if (lrow < Ne) v = *(const uint4*)(H + (size_t)(rbase + lrow) * F_DIM + kb + c8 * 8);
      unsigned bo = (unsigned)(row * (BK * 2) + c8 * 16) ^ ((row & 7) << 4);
      *(uint4*)((char*)As + bo) = v;
    }
    // stage B from w2 (f32 -> bf16)
    #pragma unroll
    for (int it = 0; it < 8; ++it) {
      int idx = it * 256 + tid;
      int row = idx >> 4, c4 = idx & 15;
      float4 v = *(const float4*)(w2e + (size_t)row * F_DIM + kb + c4 * 4);
      unsigned bo = (unsigned)(row * (BK * 2) + c4 * 8) ^ ((row & 7) << 4);
      *(uint2*)((char*)Bs + bo) = make_uint2(pack2bf(v.x, v.y), pack2bf(v.z, v.w));
    }
    __syncthreads();
    #pragma unroll
    for (int ksub = 0; ksub < 2; ++ksub) {
      int colb = (ksub * 32 + lq * 8) * 2;
      bf16x8 af[4], bfr[4];
      #pragma unroll
      for (int mi = 0; mi < 4; ++mi) {
        int row = wm * 64 + mi * 16 + lr16;
        unsigned bo = (unsigned)(row * (BK * 2) + colb) ^ ((row & 7) << 4);
        af[mi] = *(const bf16x8*)((const char*)As + bo);
      }
      #pragma unroll
      for (int ni = 0; ni < 4; ++ni) {
        int row = wn * 64 + ni * 16 + lr16;
        unsigned bo = (unsigned)(row * (BK * 2) + colb) ^ ((row & 7) << 4);
        bfr[ni] = *(const bf16x8*)((const char*)Bs + bo);
      }
      #pragma unroll
      for (int mi = 0; mi < 4; ++mi)
        #pragma unroll
        for (int ni = 0; ni < 4; ++ni)
          acc[mi][ni] = __builtin_amdgcn_mfma_f32_16x16x32_bf16(af[mi], bfr[ni], acc[mi][ni], 0, 0, 0);
    }
    __syncthreads();
  }
  #pragma unroll
  for (int mi = 0; mi < 4; ++mi) {
    int mb = wm * 64 + mi * 16 + lq * 4;
    #pragma unroll
    for (int r = 0; r < 4; ++r) {
      int lrow = mt * BM + mb + r;
      if (lrow < Ne) {
        size_t yrow = (size_t)(rbase + lrow) * D_DIM;
        #pragma unroll
        for (int ni = 0; ni < 4; ++ni) {
          int d = nt * BN + wn * 64 + ni * 16 + lr16;
          Y[yrow + d] = acc[mi][ni][r];
        }
      }
    }
  }
}

// ---------------- combine: out[t] = p0*Y[r0] + p1*Y[r1]  (writes every element; no memset needed)
__global__ __launch_bounds__(256) void moe_combine(
    const float* __restrict__ Y, const int* __restrict__ rowpos,
    const float* __restrict__ topw, float* __restrict__ out)
{
  int t = blockIdx.x, tid = threadIdx.x;
  int r0 = rowpos[t * 2], r1 = rowpos[t * 2 + 1];
  float p0 = topw[t * 2], p1 = topw[t * 2 + 1];
  float4 a = *(const float4*)(Y + (size_t)r0 * D_DIM + tid * 4);
  float4 b = *(const float4*)(Y + (size_t)r1 * D_DIM + tid * 4);
  float4 o;
  o.x = p0 * a.x + p1 * b.x;
  o.y = p0 * a.y + p1 * b.y;
  o.z = p0 * a.z + p1 * b.z;
  o.w = p0 * a.w + p1 * b.w;
  *(float4*)(out + (size_t)t * D_DIM + tid * 4) = o;
}

extern "C" void kernel_launch(void* const* d_in, const int* in_sizes, int n_in,
                              void* d_out, int out_size, void* d_ws, size_t ws_size,
                              hipStream_t stream) {
  const float* x    = (const float*)d_in[0];
  const float* gate = (const float*)d_in[1];
  const float* w1   = (const float*)d_in[2];
  const float* w2   = (const float*)d_in[3];
  const float* w3   = (const float*)d_in[4];
  float* out    = (float*)d_out;
  float* logits = out + (size_t)T_NUM * D_DIM;

  // workspace layout (needs ~48.2 MB)
  char* ws = (char*)d_ws;
  int*   cnt     = (int*)(ws + 0);
  int*   rowbase = (int*)(ws + 64);
  int*   topi    = (int*)(ws + 1024);                         // 4096 ints
  float* topw    = (float*)(ws + 1024 + 16384);               // 4096 floats
  int*   rowlist = (int*)(ws + 1024 + 32768);                 // 4096 ints
  int*   rowpos  = (int*)(ws + 1024 + 49152);                 // 4096 ints
  unsigned short* H = (unsigned short*)(ws + 131072);         // 4096*4096 bf16 = 32 MB
  float* Y = (float*)(ws + 131072 + (size_t)4096 * 4096 * 2); // 4096*1024 f32 = 16 MB

  moe_router<<<T_NUM / 16, 256, 0, stream>>>(x, gate, logits, topi, topw);
  moe_route_build<<<1, 1024, 0, stream>>>(topi, cnt, rowbase, rowlist, rowpos);
  moe_gemm1<<<dim3(F_DIM / BN, T_NUM / BM, E_NUM), 256, 0, stream>>>(x, w1, w3, cnt, rowbase, rowlist, H);
  moe_gemm2<<<dim3(D_DIM / BN, T_NUM / BM, E_NUM), 256, 0, stream>>>(H, w2, cnt, rowbase, Y);
  moe_combine<<<T_NUM, 256, 0, stream>>>(Y, rowpos, topw, out);
}

// Round 2
// 455.509 us; speedup vs baseline: 1.7539x; 1.7539x over previous
//
#include <hip/hip_runtime.h>

#define D_DIM 1024
#define F_DIM 4096
#define E_NUM 16
#define T_NUM 2048

typedef __bf16 bf16x8 __attribute__((ext_vector_type(8)));
typedef float f32x4 __attribute__((ext_vector_type(4)));

// round-to-nearest-up f32 -> bf16 pair packed into u32 (lo = a, hi = b)
__device__ __forceinline__ unsigned pack2bf(float a, float b) {
  unsigned ua = __builtin_bit_cast(unsigned, a);
  unsigned ub = __builtin_bit_cast(unsigned, b);
  return ((ub + 0x8000u) & 0xffff0000u) | ((ua + 0x8000u) >> 16);
}
__device__ __forceinline__ unsigned short f2bf(float a) {
  unsigned ua = __builtin_bit_cast(unsigned, a);
  return (unsigned short)((ua + 0x8000u) >> 16);
}
// 8 consecutive f32 -> bf16x8 MFMA fragment
__device__ __forceinline__ bf16x8 cvt8(f32x4 a, f32x4 b) {
  union { unsigned u[4]; bf16x8 v; } r;
  r.u[0] = pack2bf(a[0], a[1]); r.u[1] = pack2bf(a[2], a[3]);
  r.u[2] = pack2bf(b[0], b[1]); r.u[3] = pack2bf(b[2], b[3]);
  return r.v;
}
// async 16B global->LDS (per-lane global addr, wave-uniform LDS base + lane*16)
__device__ __forceinline__ void gload16(const void* g, void* l) {
  __builtin_amdgcn_global_load_lds(
      (const __attribute__((address_space(1))) unsigned*)g,
      (__attribute__((address_space(3))) unsigned*)l, 16, 0, 0);
}

// ---------------- router
__global__ __launch_bounds__(256) void moe_router(
    const float* __restrict__ x, const float* __restrict__ gate,
    float* __restrict__ logits_out, int* __restrict__ topi, float* __restrict__ topw)
{
  __shared__ float lg[16][17];
  int tid = threadIdx.x;
  int tbase = blockIdx.x * 16;
  int tt = tid >> 4, e = tid & 15;
  const float4* xr = (const float4*)(x + (size_t)(tbase + tt) * D_DIM);
  const float4* gw = (const float4*)(gate + (size_t)e * D_DIM);
  float acc = 0.f;
  #pragma unroll 4
  for (int k = 0; k < D_DIM / 4; ++k) {
    float4 a = xr[k], b = gw[k];
    acc += a.x * b.x + a.y * b.y + a.z * b.z + a.w * b.w;
  }
  lg[tt][e] = acc;
  logits_out[(size_t)(tbase + tt) * E_NUM + e] = acc;
  __syncthreads();
  if (tid < 16) {
    int t = tid;
    float best = -1e30f; int i0 = 0;
    #pragma unroll
    for (int j = 0; j < 16; ++j) { float v = lg[t][j]; if (v > best) { best = v; i0 = j; } }
    float best1 = -1e30f; int i1 = 0;
    #pragma unroll
    for (int j = 0; j < 16; ++j) { if (j == i0) continue; float v = lg[t][j]; if (v > best1) { best1 = v; i1 = j; } }
    float e1 = __expf(best1 - best);
    float inv = 1.f / (1.f + e1);
    int gt = tbase + t;
    topi[gt * 2]     = i0;  topi[gt * 2 + 1] = i1;
    topw[gt * 2]     = inv; topw[gt * 2 + 1] = e1 * inv;
  }
}

// ---------------- deterministic routing
__global__ __launch_bounds__(1024) void moe_route_build(
    const int* __restrict__ topi,
    int* __restrict__ cnt, int* __restrict__ rowbase,
    int* __restrict__ rowlist, int* __restrict__ rowpos)
{
  __shared__ int scnt[16];
  __shared__ int sbase[17];
  int wave = threadIdx.x >> 6;
  int lane = threadIdx.x & 63;
  int total = 0;
  for (int c = 0; c < (T_NUM * 2) / 64; ++c) {
    int s = c * 64 + lane;
    unsigned long long m = __ballot(topi[s] == wave);
    total += __popcll(m);
  }
  if (lane == 0) scnt[wave] = total;
  __syncthreads();
  if (threadIdx.x == 0) {
    int acc = 0;
    for (int e2 = 0; e2 < 16; ++e2) { sbase[e2] = acc; cnt[e2] = scnt[e2]; acc += scnt[e2]; }
    sbase[16] = acc;
    for (int e2 = 0; e2 <= 16; ++e2) rowbase[e2] = sbase[e2];
  }
  __syncthreads();
  int running = sbase[wave];
  for (int c = 0; c < (T_NUM * 2) / 64; ++c) {
    int s = c * 64 + lane;
    int ei = topi[s];
    unsigned long long m = __ballot(ei == wave);
    if (ei == wave) {
      int pos = running + __popcll(m & ((1ull << lane) - 1ull));
      rowlist[pos] = s;
      rowpos[s] = pos;
    }
    running += __popcll(m);
  }
}

// ---------------- GEMM1: H = silu(x@w1^T) * (x@w3^T)
// f32 tiles in LDS via global_load_lds (source-swizzled), convert after ds_read.
// BM=128, BN=128, BK=32. LDS 48.5 KB -> 3 blocks/CU. 1024 active blocks.
__global__ __launch_bounds__(256, 2) void moe_gemm1(
    const float* __restrict__ x, const float* __restrict__ w1s, const float* __restrict__ w3s,
    const int* __restrict__ cnt, const int* __restrict__ rowbase, const int* __restrict__ rowlist,
    unsigned short* __restrict__ H)
{
  int e = blockIdx.z, mt = blockIdx.y, nt = blockIdx.x;
  int Ne = cnt[e];
  if (mt * 128 >= Ne) return;
  int rbase = rowbase[e];

  __shared__ float Xs[128 * 32];
  __shared__ float W1t[128 * 32];
  __shared__ float W3t[128 * 32];
  __shared__ int toks[128];

  int tid = threadIdx.x;
  int lane = tid & 63, wave = tid >> 6;
  if (tid < 128) {
    int lr = mt * 128 + tid;
    toks[tid] = (lr < Ne) ? (rowlist[rbase + lr] >> 1) : 0;   // clamp pad rows to tok 0 (output guarded)
  }
  __syncthreads();

  const float* w1e = w1s + (size_t)e * F_DIM * D_DIM + (size_t)(nt * 128) * D_DIM;
  const float* w3e = w3s + (size_t)e * F_DIM * D_DIM + (size_t)(nt * 128) * D_DIM;

  // staging: each tile = 16 wave-chunks of 1024B (8 rows x 128B); wave w owns chunks w*4..w*4+3.
  // source swizzle: LDS(row, c) holds global chunk c^(row&7)  (rows are 128B = 8 x 16B chunks)
  int srow = lane >> 3, sc = lane & 7;
  const char* px[4]; const char* p1[4]; const char* p3[4];
  char *lx[4], *l1[4], *l3[4];
  #pragma unroll
  for (int it = 0; it < 4; ++it) {
    int ch = wave * 4 + it;
    int row = ch * 8 + srow;
    int gc = sc ^ (row & 7);
    px[it] = (const char*)(x + (size_t)toks[row] * D_DIM) + gc * 16;
    p1[it] = (const char*)(w1e + (size_t)row * D_DIM) + gc * 16;
    p3[it] = (const char*)(w3e + (size_t)row * D_DIM) + gc * 16;
    lx[it] = (char*)Xs  + ch * 1024;
    l1[it] = (char*)W1t + ch * 1024;
    l3[it] = (char*)W3t + ch * 1024;
  }

  int wm = wave >> 1, wn = wave & 1;
  int lr16 = lane & 15, lq = lane >> 4;

  // swizzled read byte-offsets (A: token rows, B: weight rows); 8 f32 = chunks lq*2, lq*2+1
  unsigned offA[4][2], offB[4][2];
  #pragma unroll
  for (int mi = 0; mi < 4; ++mi) {
    int row = wm * 64 + mi * 16 + lr16;
    #pragma unroll
    for (int h = 0; h < 2; ++h)
      offA[mi][h] = (unsigned)(row * 128 + (((lq * 2 + h) ^ (row & 7)) * 16));
  }
  #pragma unroll
  for (int ni = 0; ni < 4; ++ni) {
    int n = wn * 64 + ni * 16 + lr16;
    #pragma unroll
    for (int h = 0; h < 2; ++h)
      offB[ni][h] = (unsigned)(n * 128 + (((lq * 2 + h) ^ (n & 7)) * 16));
  }

  f32x4 acc1[4][4], acc3[4][4];
  #pragma unroll
  for (int i = 0; i < 4; ++i)
    #pragma unroll
    for (int j = 0; j < 4; ++j) { acc1[i][j] = {0.f,0.f,0.f,0.f}; acc3[i][j] = {0.f,0.f,0.f,0.f}; }

  for (int ks = 0; ks < D_DIM / 32; ++ks) {
    #pragma unroll
    for (int it = 0; it < 4; ++it) {
      gload16(px[it], lx[it]); px[it] += 128;
      gload16(p1[it], l1[it]); p1[it] += 128;
      gload16(p3[it], l3[it]); p3[it] += 128;
    }
    __syncthreads();   // drains vmcnt

    bf16x8 af[4], b1f[4], b3f[4];
    #pragma unroll
    for (int mi = 0; mi < 4; ++mi)
      af[mi] = cvt8(*(const f32x4*)((const char*)Xs + offA[mi][0]),
                    *(const f32x4*)((const char*)Xs + offA[mi][1]));
    #pragma unroll
    for (int ni = 0; ni < 4; ++ni) {
      b1f[ni] = cvt8(*(const f32x4*)((const char*)W1t + offB[ni][0]),
                     *(const f32x4*)((const char*)W1t + offB[ni][1]));
      b3f[ni] = cvt8(*(const f32x4*)((const char*)W3t + offB[ni][0]),
                     *(const f32x4*)((const char*)W3t + offB[ni][1]));
    }
    #pragma unroll
    for (int ni = 0; ni < 4; ++ni)
      #pragma unroll
      for (int mi = 0; mi < 4; ++mi) {
        acc1[mi][ni] = __builtin_amdgcn_mfma_f32_16x16x32_bf16(af[mi], b1f[ni], acc1[mi][ni], 0, 0, 0);
        acc3[mi][ni] = __builtin_amdgcn_mfma_f32_16x16x32_bf16(af[mi], b3f[ni], acc3[mi][ni], 0, 0, 0);
      }
    __syncthreads();
  }

  #pragma unroll
  for (int mi = 0; mi < 4; ++mi) {
    int mb = wm * 64 + mi * 16 + lq * 4;
    #pragma unroll
    for (int r = 0; r < 4; ++r) {
      int lrow = mt * 128 + mb + r;
      if (lrow < Ne) {
        size_t hrow = (size_t)(rbase + lrow) * F_DIM;
        #pragma unroll
        for (int ni = 0; ni < 4; ++ni) {
          int f = nt * 128 + wn * 64 + ni * 16 + lr16;
          float a1v = acc1[mi][ni][r];
          float a3v = acc3[mi][ni][r];
          float hv = (a1v / (1.f + __expf(-a1v))) * a3v;
          H[hrow + f] = f2bf(hv);
        }
      }
    }
  }
}

// ---------------- GEMM2: Y = H @ w2^T
// BM=128, BN=64, BK=64. A = H bf16 (direct), B = w2 f32 (convert). LDS 32 KB. 512 active blocks.
__global__ __launch_bounds__(256, 2) void moe_gemm2(
    const unsigned short* __restrict__ H, const float* __restrict__ w2s,
    const int* __restrict__ cnt, const int* __restrict__ rowbase,
    float* __restrict__ Y)
{
  int e = blockIdx.z, mt = blockIdx.y, nt = blockIdx.x;
  int Ne = cnt[e];
  if (mt * 128 >= Ne) return;
  int rbase = rowbase[e];

  __shared__ unsigned short As[128 * 64];  // bf16, rows 128B
  __shared__ float Bs[64 * 64];            // f32, rows 256B

  int tid = threadIdx.x;
  int lane = tid & 63, wave = tid >> 6;

  const float* w2e = w2s + (size_t)e * D_DIM * F_DIM + (size_t)(nt * 64) * F_DIM;

  // A staging: 16 chunks (8 rows x 128B each); clamp pad rows
  int srow = lane >> 3, sc = lane & 7;
  const char* pa[4]; char* la[4];
  #pragma unroll
  for (int it = 0; it < 4; ++it) {
    int ch = wave * 4 + it;
    int row = ch * 8 + srow;
    int gc = sc ^ (row & 7);
    int grow = mt * 128 + row; if (grow >= Ne) grow = Ne - 1;
    pa[it] = (const char*)(H + (size_t)(rbase + grow) * F_DIM) + gc * 16;
    la[it] = (char*)As + ch * 1024;
  }
  // B staging: 16 chunks (4 rows x 256B each); rows are 16 x 16B chunks
  int srow4 = lane >> 4, sc16 = lane & 15;
  const char* pb[4]; char* lb[4];
  #pragma unroll
  for (int it = 0; it < 4; ++it) {
    int ch = wave * 4 + it;
    int row = ch * 4 + srow4;
    int gc = sc16 ^ (row & 7);
    pb[it] = (const char*)(w2e + (size_t)row * F_DIM) + gc * 16;
    lb[it] = (char*)Bs + ch * 1024;
  }

  int wm = wave >> 1, wn = wave & 1;
  int lr16 = lane & 15, lq = lane >> 4;

  f32x4 acc[4][2];
  #pragma unroll
  for (int i = 0; i < 4; ++i) { acc[i][0] = {0.f,0.f,0.f,0.f}; acc[i][1] = {0.f,0.f,0.f,0.f}; }

  for (int ks = 0; ks < F_DIM / 64; ++ks) {
    #pragma unroll
    for (int it = 0; it < 4; ++it) {
      gload16(pa[it], la[it]); pa[it] += 128;
      gload16(pb[it], lb[it]); pb[it] += 256;
    }
    __syncthreads();

    #pragma unroll
    for (int ksub = 0; ksub < 2; ++ksub) {
      bf16x8 af[4], bf[2];
      #pragma unroll
      for (int mi = 0; mi < 4; ++mi) {
        int row = wm * 64 + mi * 16 + lr16;
        unsigned off = (unsigned)(row * 128 + (((ksub * 4 + lq) ^ (row & 7)) * 16));
        af[mi] = *(const bf16x8*)((const char*)As + off);
      }
      #pragma unroll
      for (int ni = 0; ni < 2; ++ni) {
        int n = wn * 32 + ni * 16 + lr16;
        unsigned o0 = (unsigned)(n * 256 + (((ksub * 8 + lq * 2 + 0) ^ (n & 7)) * 16));
        unsigned o1 = (unsigned)(n * 256 + (((ksub * 8 + lq * 2 + 1) ^ (n & 7)) * 16));
        bf[ni] = cvt8(*(const f32x4*)((const char*)Bs + o0),
                      *(const f32x4*)((const char*)Bs + o1));
      }
      #pragma unroll
      for (int mi = 0; mi < 4; ++mi)
        #pragma unroll
        for (int ni = 0; ni < 2; ++ni)
          acc[mi][ni] = __builtin_amdgcn_mfma_f32_16x16x32_bf16(af[mi], bf[ni], acc[mi][ni], 0, 0, 0);
    }
    __syncthreads();
  }

  #pragma unroll
  for (int mi = 0; mi < 4; ++mi) {
    int mb = wm * 64 + mi * 16 + lq * 4;
    #pragma unroll
    for (int r = 0; r < 4; ++r) {
      int lrow = mt * 128 + mb + r;
      if (lrow < Ne) {
        size_t yrow = (size_t)(rbase + lrow) * D_DIM;
        #pragma unroll
        for (int ni = 0; ni < 2; ++ni) {
          int d = nt * 64 + wn * 32 + ni * 16 + lr16;
          Y[yrow + d] = acc[mi][ni][r];
        }
      }
    }
  }
}

// ---------------- combine
__global__ __launch_bounds__(256) void moe_combine(
    const float* __restrict__ Y, const int* __restrict__ rowpos,
    const float* __restrict__ topw, float* __restrict__ out)
{
  int t = blockIdx.x, tid = threadIdx.x;
  int r0 = rowpos[t * 2], r1 = rowpos[t * 2 + 1];
  float p0 = topw[t * 2], p1 = topw[t * 2 + 1];
  float4 a = *(const float4*)(Y + (size_t)r0 * D_DIM + tid * 4);
  float4 b = *(const float4*)(Y + (size_t)r1 * D_DIM + tid * 4);
  float4 o;
  o.x = p0 * a.x + p1 * b.x;
  o.y = p0 * a.y + p1 * b.y;
  o.z = p0 * a.z + p1 * b.z;
  o.w = p0 * a.w + p1 * b.w;
  *(float4*)(out + (size_t)t * D_DIM + tid * 4) = o;
}

extern "C" void kernel_launch(void* const* d_in, const int* in_sizes, int n_in,
                              void* d_out, int out_size, void* d_ws, size_t ws_size,
                              hipStream_t stream) {
  const float* x    = (const float*)d_in[0];
  const float* gate = (const float*)d_in[1];
  const float* w1   = (const float*)d_in[2];
  const float* w2   = (const float*)d_in[3];
  const float* w3   = (const float*)d_in[4];
  float* out    = (float*)d_out;
  float* logits = out + (size_t)T_NUM * D_DIM;

  char* ws = (char*)d_ws;
  int*   cnt     = (int*)(ws + 0);
  int*   rowbase = (int*)(ws + 64);
  int*   topi    = (int*)(ws + 1024);
  float* topw    = (float*)(ws + 1024 + 16384);
  int*   rowlist = (int*)(ws + 1024 + 32768);
  int*   rowpos  = (int*)(ws + 1024 + 49152);
  unsigned short* H = (unsigned short*)(ws + 131072);
  float* Y = (float*)(ws + 131072 + (size_t)4096 * 4096 * 2);

  moe_router<<<T_NUM / 16, 256, 0, stream>>>(x, gate, logits, topi, topw);
  moe_route_build<<<1, 1024, 0, stream>>>(topi, cnt, rowbase, rowlist, rowpos);
  moe_gemm1<<<dim3(F_DIM / 128, T_NUM / 128, E_NUM), 256, 0, stream>>>(x, w1, w3, cnt, rowbase, rowlist, H);
  moe_gemm2<<<dim3(D_DIM / 64, T_NUM / 128, E_NUM), 256, 0, stream>>>(H, w2, cnt, rowbase, Y);
  moe_combine<<<T_NUM, 256, 0, stream>>>(Y, rowpos, topw, out);
}

// Round 4
// 367.889 us; speedup vs baseline: 2.1717x; 1.2382x over previous
//
#include <hip/hip_runtime.h>

#define D_DIM 1024
#define F_DIM 4096
#define E_NUM 16
#define T_NUM 2048

typedef __bf16 bf16x8 __attribute__((ext_vector_type(8)));
typedef float f32x4 __attribute__((ext_vector_type(4)));

__device__ __forceinline__ unsigned pack2bf(float a, float b) {
  unsigned ua = __builtin_bit_cast(unsigned, a);
  unsigned ub = __builtin_bit_cast(unsigned, b);
  return ((ub + 0x8000u) & 0xffff0000u) | ((ua + 0x8000u) >> 16);
}
__device__ __forceinline__ unsigned short f2bf(float a) {
  unsigned ua = __builtin_bit_cast(unsigned, a);
  return (unsigned short)((ua + 0x8000u) >> 16);
}
__device__ __forceinline__ bf16x8 cvt8(f32x4 a, f32x4 b) {
  union { unsigned u[4]; bf16x8 v; } r;
  r.u[0] = pack2bf(a[0], a[1]); r.u[1] = pack2bf(a[2], a[3]);
  r.u[2] = pack2bf(b[0], b[1]); r.u[3] = pack2bf(b[2], b[3]);
  return r.v;
}
__device__ __forceinline__ void gload16(const void* g, void* l) {
  __builtin_amdgcn_global_load_lds(
      (const __attribute__((address_space(1))) unsigned*)g,
      (__attribute__((address_space(3))) unsigned*)l, 16, 0, 0);
}

// ---------------- x -> bf16 pre-pass
__global__ __launch_bounds__(256) void moe_xcast(
    const float* __restrict__ x, unsigned short* __restrict__ xbf)
{
  int i = blockIdx.x * 256 + threadIdx.x;          // 8 floats per thread
  const f32x4* p = (const f32x4*)x + (size_t)i * 2;
  f32x4 a = p[0], b = p[1];
  uint4 o;
  o.x = pack2bf(a[0], a[1]); o.y = pack2bf(a[2], a[3]);
  o.z = pack2bf(b[0], b[1]); o.w = pack2bf(b[2], b[3]);
  ((uint4*)xbf)[i] = o;
}

// ---------------- router
__global__ __launch_bounds__(256) void moe_router(
    const float* __restrict__ x, const float* __restrict__ gate,
    float* __restrict__ logits_out, int* __restrict__ topi, float* __restrict__ topw)
{
  __shared__ float lg[16][17];
  int tid = threadIdx.x;
  int tbase = blockIdx.x * 16;
  int tt = tid >> 4, e = tid & 15;
  const float4* xr = (const float4*)(x + (size_t)(tbase + tt) * D_DIM);
  const float4* gw = (const float4*)(gate + (size_t)e * D_DIM);
  float acc = 0.f;
  #pragma unroll 4
  for (int k = 0; k < D_DIM / 4; ++k) {
    float4 a = xr[k], b = gw[k];
    acc += a.x * b.x + a.y * b.y + a.z * b.z + a.w * b.w;
  }
  lg[tt][e] = acc;
  logits_out[(size_t)(tbase + tt) * E_NUM + e] = acc;
  __syncthreads();
  if (tid < 16) {
    int t = tid;
    float best = -1e30f; int i0 = 0;
    #pragma unroll
    for (int j = 0; j < 16; ++j) { float v = lg[t][j]; if (v > best) { best = v; i0 = j; } }
    float best1 = -1e30f; int i1 = 0;
    #pragma unroll
    for (int j = 0; j < 16; ++j) { if (j == i0) continue; float v = lg[t][j]; if (v > best1) { best1 = v; i1 = j; } }
    float e1 = __expf(best1 - best);
    float inv = 1.f / (1.f + e1);
    int gt = tbase + t;
    topi[gt * 2]     = i0;  topi[gt * 2 + 1] = i1;
    topw[gt * 2]     = inv; topw[gt * 2 + 1] = e1 * inv;
  }
}

// ---------------- deterministic routing
__global__ __launch_bounds__(1024) void moe_route_build(
    const int* __restrict__ topi,
    int* __restrict__ cnt, int* __restrict__ rowbase,
    int* __restrict__ rowlist, int* __restrict__ rowpos)
{
  __shared__ int scnt[16];
  __shared__ int sbase[17];
  int wave = threadIdx.x >> 6;
  int lane = threadIdx.x & 63;
  int total = 0;
  for (int c = 0; c < (T_NUM * 2) / 64; ++c) {
    int s = c * 64 + lane;
    unsigned long long m = __ballot(topi[s] == wave);
    total += __popcll(m);
  }
  if (lane == 0) scnt[wave] = total;
  __syncthreads();
  if (threadIdx.x == 0) {
    int acc = 0;
    for (int e2 = 0; e2 < 16; ++e2) { sbase[e2] = acc; cnt[e2] = scnt[e2]; acc += scnt[e2]; }
    sbase[16] = acc;
    for (int e2 = 0; e2 <= 16; ++e2) rowbase[e2] = sbase[e2];
  }
  __syncthreads();
  int running = sbase[wave];
  for (int c = 0; c < (T_NUM * 2) / 64; ++c) {
    int s = c * 64 + lane;
    int ei = topi[s];
    unsigned long long m = __ballot(ei == wave);
    if (ei == wave) {
      int pos = running + __popcll(m & ((1ull << lane) - 1ull));
      rowlist[pos] = s;
      rowpos[s] = pos;
    }
    running += __popcll(m);
  }
}

// ---------------- GEMM1: H = silu(x@w1^T) * (x@w3^T)
// BM=128 BN=128 BK=32, double-buffered gload_lds pipeline (stage t+1 before compute t).
// LDS layout (byte offsets in one __shared__ block, 81920 B -> 2 blocks/CU):
//   X bufs:  0, 8192   (8 KB each, bf16)
//   W1 bufs: 16384, 32768  (16 KB each, f32)
//   W3 bufs: 49152, 65536
__global__ __launch_bounds__(256, 2) void moe_gemm1(
    const unsigned short* __restrict__ xbf, const float* __restrict__ w1s, const float* __restrict__ w3s,
    const int* __restrict__ cnt, const int* __restrict__ rowbase, const int* __restrict__ rowlist,
    unsigned short* __restrict__ H)
{
  int e = blockIdx.z, mt = blockIdx.y, nt = blockIdx.x;
  int Ne = cnt[e];
  if (mt * 128 >= Ne) return;
  int rbase = rowbase[e];

  __shared__ char smem[81920];

  int tid = threadIdx.x, lane = tid & 63, wave = tid >> 6;

  // X staging: 8 chunks of 1KB (16 rows x 64B); wave owns chunks wave*2, wave*2+1.
  // source swizzle: LDS pos p holds global k-chunk p^(row&3)
  const char* px[2];
  #pragma unroll
  for (int it = 0; it < 2; ++it) {
    int r = (wave * 2 + it) * 16 + (lane >> 2);
    int lr = mt * 128 + r;
    int tok = (lr < Ne) ? (rowlist[rbase + lr] >> 1) : 0;
    int c = (lane & 3) ^ (r & 3);
    px[it] = (const char*)(xbf + (size_t)tok * D_DIM) + c * 16;
  }
  // W staging: 16 chunks of 1KB (8 rows x 128B); wave owns chunks wave*4..+3.
  const float* w1e = w1s + (size_t)e * F_DIM * D_DIM + (size_t)(nt * 128) * D_DIM;
  const float* w3e = w3s + (size_t)e * F_DIM * D_DIM + (size_t)(nt * 128) * D_DIM;
  const char* p1[4]; const char* p3[4];
  #pragma unroll
  for (int it = 0; it < 4; ++it) {
    int r = (wave * 4 + it) * 8 + (lane >> 3);
    int c = (lane & 7) ^ (r & 7);
    p1[it] = (const char*)(w1e + (size_t)r * D_DIM) + c * 16;
    p3[it] = (const char*)(w3e + (size_t)r * D_DIM) + c * 16;
  }

  int wm = wave >> 1, wn = wave & 1;
  int lr16 = lane & 15, lq = lane >> 4;

  unsigned offA[4];
  #pragma unroll
  for (int mi = 0; mi < 4; ++mi) {
    int m = wm * 64 + mi * 16 + lr16;
    offA[mi] = (unsigned)(m * 64 + ((lq ^ (m & 3)) * 16));
  }
  unsigned offB[4][2];
  #pragma unroll
  for (int ni = 0; ni < 4; ++ni) {
    int n = wn * 64 + ni * 16 + lr16;
    #pragma unroll
    for (int h = 0; h < 2; ++h)
      offB[ni][h] = (unsigned)(n * 128 + (((lq * 2 + h) ^ (n & 7)) * 16));
  }

  f32x4 acc1[4][4], acc3[4][4];
  #pragma unroll
  for (int i = 0; i < 4; ++i)
    #pragma unroll
    for (int j = 0; j < 4; ++j) { acc1[i][j] = {0.f,0.f,0.f,0.f}; acc3[i][j] = {0.f,0.f,0.f,0.f}; }

  // stage destinations as byte offsets from smem
  unsigned xdst = (unsigned)((wave * 2) * 1024 + lane * 16);
  unsigned wdst = (unsigned)((wave * 4) * 1024 + lane * 16);

  auto STAGE = [&](unsigned bsel, int ks) {
    gload16(px[0] + ks * 64, smem + bsel * 8192 + xdst);
    gload16(px[1] + ks * 64, smem + bsel * 8192 + xdst + 1024);
    #pragma unroll
    for (int it = 0; it < 4; ++it) {
      gload16(p1[it] + ks * 128, smem + 16384 + bsel * 16384 + wdst + it * 1024);
      gload16(p3[it] + ks * 128, smem + 49152 + bsel * 16384 + wdst + it * 1024);
    }
  };

  STAGE(0, 0);
  __syncthreads();
  unsigned buf = 0;
  for (int ks = 0; ks < 32; ++ks) {
    if (ks < 31) STAGE(buf ^ 1u, ks + 1);     // loads for t+1 fly under compute of t
    unsigned xb = buf * 8192;
    unsigned w1b = 16384 + buf * 16384;
    unsigned w3b = 49152 + buf * 16384;
    bf16x8 af[4], b1f[4], b3f[4];
    #pragma unroll
    for (int mi = 0; mi < 4; ++mi)
      af[mi] = *(const bf16x8*)(smem + xb + offA[mi]);
    #pragma unroll
    for (int ni = 0; ni < 4; ++ni) {
      b1f[ni] = cvt8(*(const f32x4*)(smem + w1b + offB[ni][0]),
                     *(const f32x4*)(smem + w1b + offB[ni][1]));
      b3f[ni] = cvt8(*(const f32x4*)(smem + w3b + offB[ni][0]),
                     *(const f32x4*)(smem + w3b + offB[ni][1]));
    }
    #pragma unroll
    for (int ni = 0; ni < 4; ++ni)
      #pragma unroll
      for (int mi = 0; mi < 4; ++mi) {
        acc1[mi][ni] = __builtin_amdgcn_mfma_f32_16x16x32_bf16(af[mi], b1f[ni], acc1[mi][ni], 0, 0, 0);
        acc3[mi][ni] = __builtin_amdgcn_mfma_f32_16x16x32_bf16(af[mi], b3f[ni], acc3[mi][ni], 0, 0, 0);
      }
    __syncthreads();                          // drains vmcnt: buf^1 ready, buf free
    buf ^= 1u;
  }

  #pragma unroll
  for (int mi = 0; mi < 4; ++mi) {
    int mb = wm * 64 + mi * 16 + lq * 4;
    #pragma unroll
    for (int r = 0; r < 4; ++r) {
      int lrow = mt * 128 + mb + r;
      if (lrow < Ne) {
        size_t hrow = (size_t)(rbase + lrow) * F_DIM;
        #pragma unroll
        for (int ni = 0; ni < 4; ++ni) {
          int f = nt * 128 + wn * 64 + ni * 16 + lr16;
          float a1v = acc1[mi][ni][r];
          float a3v = acc3[mi][ni][r];
          float hv = (a1v / (1.f + __expf(-a1v))) * a3v;
          H[hrow + f] = f2bf(hv);
        }
      }
    }
  }
}

// ---------------- GEMM2: Y = H @ w2^T (bf16 out), same pipeline
// BM=128 BN=64 BK=64; LDS: A bufs 0/16384, B bufs 32768/49152 (65536 B total).
__global__ __launch_bounds__(256, 2) void moe_gemm2(
    const unsigned short* __restrict__ H, const float* __restrict__ w2s,
    const int* __restrict__ cnt, const int* __restrict__ rowbase,
    unsigned short* __restrict__ Ybf)
{
  int e = blockIdx.z, mt = blockIdx.y, nt = blockIdx.x;
  int Ne = cnt[e];
  if (mt * 128 >= Ne) return;
  int rbase = rowbase[e];

  __shared__ char smem[65536];

  int tid = threadIdx.x, lane = tid & 63, wave = tid >> 6;

  const char* pa[4];
  #pragma unroll
  for (int it = 0; it < 4; ++it) {
    int r = (wave * 4 + it) * 8 + (lane >> 3);
    int c = (lane & 7) ^ (r & 7);
    int grow = mt * 128 + r; if (grow >= Ne) grow = Ne - 1;
    pa[it] = (const char*)(H + (size_t)(rbase + grow) * F_DIM) + c * 16;
  }
  const float* w2e = w2s + (size_t)e * D_DIM * F_DIM + (size_t)(nt * 64) * F_DIM;
  const char* pb[4];
  #pragma unroll
  for (int it = 0; it < 4; ++it) {
    int r = (wave * 4 + it) * 4 + (lane >> 4);
    int c = (lane & 15) ^ (r & 7);
    pb[it] = (const char*)(w2e + (size_t)r * F_DIM) + c * 16;
  }

  int wm = wave >> 1, wn = wave & 1;
  int lr16 = lane & 15, lq = lane >> 4;

  f32x4 acc[4][2];
  #pragma unroll
  for (int i = 0; i < 4; ++i) { acc[i][0] = {0.f,0.f,0.f,0.f}; acc[i][1] = {0.f,0.f,0.f,0.f}; }

  unsigned dst = (unsigned)((wave * 4) * 1024 + lane * 16);

  auto STAGE = [&](unsigned bsel, int ks) {
    #pragma unroll
    for (int it = 0; it < 4; ++it) {
      gload16(pa[it] + ks * 128, smem + bsel * 16384 + dst + it * 1024);
      gload16(pb[it] + ks * 256, smem + 32768 + bsel * 16384 + dst + it * 1024);
    }
  };

  STAGE(0, 0);
  __syncthreads();
  unsigned buf = 0;
  for (int ks = 0; ks < 64; ++ks) {
    if (ks < 63) STAGE(buf ^ 1u, ks + 1);
    unsigned ab = buf * 16384;
    unsigned bb = 32768 + buf * 16384;
    #pragma unroll
    for (int ksub = 0; ksub < 2; ++ksub) {
      bf16x8 af[4], bf[2];
      #pragma unroll
      for (int mi = 0; mi < 4; ++mi) {
        int m = wm * 64 + mi * 16 + lr16;
        unsigned off = (unsigned)(m * 128 + (((ksub * 4 + lq) ^ (m & 7)) * 16));
        af[mi] = *(const bf16x8*)(smem + ab + off);
      }
      #pragma unroll
      for (int ni = 0; ni < 2; ++ni) {
        int n = wn * 32 + ni * 16 + lr16;
        unsigned o0 = (unsigned)(n * 256 + (((ksub * 8 + lq * 2 + 0) ^ (n & 7)) * 16));
        unsigned o1 = (unsigned)(n * 256 + (((ksub * 8 + lq * 2 + 1) ^ (n & 7)) * 16));
        bf[ni] = cvt8(*(const f32x4*)(smem + bb + o0), *(const f32x4*)(smem + bb + o1));
      }
      #pragma unroll
      for (int mi = 0; mi < 4; ++mi)
        #pragma unroll
        for (int ni = 0; ni < 2; ++ni)
          acc[mi][ni] = __builtin_amdgcn_mfma_f32_16x16x32_bf16(af[mi], bf[ni], acc[mi][ni], 0, 0, 0);
    }
    __syncthreads();
    buf ^= 1u;
  }

  #pragma unroll
  for (int mi = 0; mi < 4; ++mi) {
    int mb = wm * 64 + mi * 16 + lq * 4;
    #pragma unroll
    for (int r = 0; r < 4; ++r) {
      int lrow = mt * 128 + mb + r;
      if (lrow < Ne) {
        size_t yrow = (size_t)(rbase + lrow) * D_DIM;
        #pragma unroll
        for (int ni = 0; ni < 2; ++ni) {
          int d = nt * 64 + wn * 32 + ni * 16 + lr16;
          Ybf[yrow + d] = f2bf(acc[mi][ni][r]);
        }
      }
    }
  }
}

// ---------------- combine
__global__ __launch_bounds__(128) void moe_combine(
    const unsigned short* __restrict__ Ybf, const int* __restrict__ rowpos,
    const float* __restrict__ topw, float* __restrict__ out)
{
  int t = blockIdx.x, tid = threadIdx.x;   // 8 cols per thread
  int r0 = rowpos[t * 2], r1 = rowpos[t * 2 + 1];
  float p0 = topw[t * 2], p1 = topw[t * 2 + 1];
  uint4 a = ((const uint4*)(Ybf + (size_t)r0 * D_DIM))[tid];
  uint4 b = ((const uint4*)(Ybf + (size_t)r1 * D_DIM))[tid];
  float4 o0, o1;
  #define LO(u) __builtin_bit_cast(float, (unsigned)((u) << 16))
  #define HI(u) __builtin_bit_cast(float, (unsigned)((u) & 0xffff0000u))
  o0.x = p0 * LO(a.x) + p1 * LO(b.x);  o0.y = p0 * HI(a.x) + p1 * HI(b.x);
  o0.z = p0 * LO(a.y) + p1 * LO(b.y);  o0.w = p0 * HI(a.y) + p1 * HI(b.y);
  o1.x = p0 * LO(a.z) + p1 * LO(b.z);  o1.y = p0 * HI(a.z) + p1 * HI(b.z);
  o1.z = p0 * LO(a.w) + p1 * LO(b.w);  o1.w = p0 * HI(a.w) + p1 * HI(b.w);
  #undef LO
  #undef HI
  float4* orow = (float4*)(out + (size_t)t * D_DIM);
  orow[tid * 2]     = o0;
  orow[tid * 2 + 1] = o1;
}

extern "C" void kernel_launch(void* const* d_in, const int* in_sizes, int n_in,
                              void* d_out, int out_size, void* d_ws, size_t ws_size,
                              hipStream_t stream) {
  const float* x    = (const float*)d_in[0];
  const float* gate = (const float*)d_in[1];
  const float* w1   = (const float*)d_in[2];
  const float* w2   = (const float*)d_in[3];
  const float* w3   = (const float*)d_in[4];
  float* out    = (float*)d_out;
  float* logits = out + (size_t)T_NUM * D_DIM;

  char* ws = (char*)d_ws;
  int*   cnt     = (int*)(ws + 0);
  int*   rowbase = (int*)(ws + 64);
  int*   topi    = (int*)(ws + 1024);
  float* topw    = (float*)(ws + 1024 + 16384);
  int*   rowlist = (int*)(ws + 1024 + 32768);
  int*   rowpos  = (int*)(ws + 1024 + 49152);
  unsigned short* H   = (unsigned short*)(ws + 131072);                      // 32 MB
  unsigned short* Ybf = (unsigned short*)(ws + 131072 + 33554432);           // 8 MB
  unsigned short* xbf = (unsigned short*)(ws + 131072 + 33554432 + 8388608); // 4 MB

  moe_xcast<<<(T_NUM * D_DIM) / (256 * 8), 256, 0, stream>>>(x, xbf);
  moe_router<<<T_NUM / 16, 256, 0, stream>>>(x, gate, logits, topi, topw);
  moe_route_build<<<1, 1024, 0, stream>>>(topi, cnt, rowbase, rowlist, rowpos);
  moe_gemm1<<<dim3(F_DIM / 128, T_NUM / 128, E_NUM), 256, 0, stream>>>(xbf, w1, w3, cnt, rowbase, rowlist, H);
  moe_gemm2<<<dim3(D_DIM / 64, T_NUM / 128, E_NUM), 256, 0, stream>>>(H, w2, cnt, rowbase, Ybf);
  moe_combine<<<T_NUM, 128, 0, stream>>>(Ybf, rowpos, topw, out);
}

// Round 5
// 365.739 us; speedup vs baseline: 2.1844x; 1.0059x over previous
//
#include <hip/hip_runtime.h>

#define D_DIM 1024
#define F_DIM 4096
#define E_NUM 16
#define T_NUM 2048

typedef __bf16 bf16x8 __attribute__((ext_vector_type(8)));
typedef float f32x4 __attribute__((ext_vector_type(4)));

__device__ __forceinline__ unsigned pack2bf(float a, float b) {
  unsigned ua = __builtin_bit_cast(unsigned, a);
  unsigned ub = __builtin_bit_cast(unsigned, b);
  return ((ub + 0x8000u) & 0xffff0000u) | ((ua + 0x8000u) >> 16);
}
__device__ __forceinline__ unsigned short f2bf(float a) {
  unsigned ua = __builtin_bit_cast(unsigned, a);
  return (unsigned short)((ua + 0x8000u) >> 16);
}
// 8 f32 -> bf16x8 via native RNE casts (compiler emits packed cvt)
__device__ __forceinline__ bf16x8 cvt8(f32x4 a, f32x4 b) {
  bf16x8 r;
  r[0] = (__bf16)a[0]; r[1] = (__bf16)a[1]; r[2] = (__bf16)a[2]; r[3] = (__bf16)a[3];
  r[4] = (__bf16)b[0]; r[5] = (__bf16)b[1]; r[6] = (__bf16)b[2]; r[7] = (__bf16)b[3];
  return r;
}
__device__ __forceinline__ void gload16(const void* g, void* l) {
  __builtin_amdgcn_global_load_lds(
      (const __attribute__((address_space(1))) unsigned*)g,
      (__attribute__((address_space(3))) unsigned*)l, 16, 0, 0);
}

// ---------------- x -> bf16 pre-pass
__global__ __launch_bounds__(256) void moe_xcast(
    const float* __restrict__ x, unsigned short* __restrict__ xbf)
{
  int i = blockIdx.x * 256 + threadIdx.x;          // 8 floats per thread
  const f32x4* p = (const f32x4*)x + (size_t)i * 2;
  f32x4 a = p[0], b = p[1];
  uint4 o;
  o.x = pack2bf(a[0], a[1]); o.y = pack2bf(a[2], a[3]);
  o.z = pack2bf(b[0], b[1]); o.w = pack2bf(b[2], b[3]);
  ((uint4*)xbf)[i] = o;
}

// ---------------- router
__global__ __launch_bounds__(256) void moe_router(
    const float* __restrict__ x, const float* __restrict__ gate,
    float* __restrict__ logits_out, int* __restrict__ topi, float* __restrict__ topw)
{
  __shared__ float lg[16][17];
  int tid = threadIdx.x;
  int tbase = blockIdx.x * 16;
  int tt = tid >> 4, e = tid & 15;
  const float4* xr = (const float4*)(x + (size_t)(tbase + tt) * D_DIM);
  const float4* gw = (const float4*)(gate + (size_t)e * D_DIM);
  float acc = 0.f;
  #pragma unroll 4
  for (int k = 0; k < D_DIM / 4; ++k) {
    float4 a = xr[k], b = gw[k];
    acc += a.x * b.x + a.y * b.y + a.z * b.z + a.w * b.w;
  }
  lg[tt][e] = acc;
  logits_out[(size_t)(tbase + tt) * E_NUM + e] = acc;
  __syncthreads();
  if (tid < 16) {
    int t = tid;
    float best = -1e30f; int i0 = 0;
    #pragma unroll
    for (int j = 0; j < 16; ++j) { float v = lg[t][j]; if (v > best) { best = v; i0 = j; } }
    float best1 = -1e30f; int i1 = 0;
    #pragma unroll
    for (int j = 0; j < 16; ++j) { if (j == i0) continue; float v = lg[t][j]; if (v > best1) { best1 = v; i1 = j; } }
    float e1 = __expf(best1 - best);
    float inv = 1.f / (1.f + e1);
    int gt = tbase + t;
    topi[gt * 2]     = i0;  topi[gt * 2 + 1] = i1;
    topw[gt * 2]     = inv; topw[gt * 2 + 1] = e1 * inv;
  }
}

// ---------------- deterministic routing
__global__ __launch_bounds__(1024) void moe_route_build(
    const int* __restrict__ topi,
    int* __restrict__ cnt, int* __restrict__ rowbase,
    int* __restrict__ rowlist, int* __restrict__ rowpos)
{
  __shared__ int scnt[16];
  __shared__ int sbase[17];
  int wave = threadIdx.x >> 6;
  int lane = threadIdx.x & 63;
  int total = 0;
  for (int c = 0; c < (T_NUM * 2) / 64; ++c) {
    int s = c * 64 + lane;
    unsigned long long m = __ballot(topi[s] == wave);
    total += __popcll(m);
  }
  if (lane == 0) scnt[wave] = total;
  __syncthreads();
  if (threadIdx.x == 0) {
    int acc = 0;
    for (int e2 = 0; e2 < 16; ++e2) { sbase[e2] = acc; cnt[e2] = scnt[e2]; acc += scnt[e2]; }
    sbase[16] = acc;
    for (int e2 = 0; e2 <= 16; ++e2) rowbase[e2] = sbase[e2];
  }
  __syncthreads();
  int running = sbase[wave];
  for (int c = 0; c < (T_NUM * 2) / 64; ++c) {
    int s = c * 64 + lane;
    int ei = topi[s];
    unsigned long long m = __ballot(ei == wave);
    if (ei == wave) {
      int pos = running + __popcll(m & ((1ull << lane) - 1ull));
      rowlist[pos] = s;
      rowpos[s] = pos;
    }
    running += __popcll(m);
  }
}

// ---------------- GEMM1: H = silu(x@w1^T) * (x@w3^T)
// BM=128 BN=128 BK=32; double-buffered gload_lds with COUNTED vmcnt barriers:
//   STAGE(t+1) -> s_waitcnt vmcnt(10) -> s_barrier -> compute(t) -> s_barrier
// (10 newest outstanding loads = t+1's; in-order retirement => t's landed.)
__global__ __launch_bounds__(256, 2) void moe_gemm1(
    const unsigned short* __restrict__ xbf, const float* __restrict__ w1s, const float* __restrict__ w3s,
    const int* __restrict__ cnt, const int* __restrict__ rowbase, const int* __restrict__ rowlist,
    unsigned short* __restrict__ H)
{
  int e = blockIdx.z, mt = blockIdx.y, nt = blockIdx.x;
  int Ne = cnt[e];
  if (mt * 128 >= Ne) return;
  int rbase = rowbase[e];

  __shared__ char smem[81920];

  int tid = threadIdx.x, lane = tid & 63, wave = tid >> 6;

  // X staging: 8 chunks of 1KB (16 rows x 64B); swizzle: slot p holds global chunk p^((r>>1)&3)
  const char* px[2];
  #pragma unroll
  for (int it = 0; it < 2; ++it) {
    int r = (wave * 2 + it) * 16 + (lane >> 2);
    int lr = mt * 128 + r;
    int tok = (lr < Ne) ? (rowlist[rbase + lr] >> 1) : 0;
    int c = (lane & 3) ^ ((r >> 1) & 3);
    px[it] = (const char*)(xbf + (size_t)tok * D_DIM) + c * 16;
  }
  // W staging: 16 chunks of 1KB (8 rows x 128B); slot p holds global chunk p^(r&7)
  const float* w1e = w1s + (size_t)e * F_DIM * D_DIM + (size_t)(nt * 128) * D_DIM;
  const float* w3e = w3s + (size_t)e * F_DIM * D_DIM + (size_t)(nt * 128) * D_DIM;
  const char* p1[4]; const char* p3[4];
  #pragma unroll
  for (int it = 0; it < 4; ++it) {
    int r = (wave * 4 + it) * 8 + (lane >> 3);
    int c = (lane & 7) ^ (r & 7);
    p1[it] = (const char*)(w1e + (size_t)r * D_DIM) + c * 16;
    p3[it] = (const char*)(w3e + (size_t)r * D_DIM) + c * 16;
  }

  int wm = wave >> 1, wn = wave & 1;
  int lr16 = lane & 15, lq = lane >> 4;

  unsigned offA[4];
  #pragma unroll
  for (int mi = 0; mi < 4; ++mi) {
    int m = wm * 64 + mi * 16 + lr16;
    offA[mi] = (unsigned)(m * 64 + ((lq ^ ((m >> 1) & 3)) * 16));
  }
  unsigned offB[4][2];
  #pragma unroll
  for (int ni = 0; ni < 4; ++ni) {
    int n = wn * 64 + ni * 16 + lr16;
    #pragma unroll
    for (int h = 0; h < 2; ++h)
      offB[ni][h] = (unsigned)(n * 128 + (((lq * 2 + h) ^ (n & 7)) * 16));
  }

  f32x4 acc1[4][4], acc3[4][4];
  #pragma unroll
  for (int i = 0; i < 4; ++i)
    #pragma unroll
    for (int j = 0; j < 4; ++j) { acc1[i][j] = {0.f,0.f,0.f,0.f}; acc3[i][j] = {0.f,0.f,0.f,0.f}; }

  unsigned xdst = (unsigned)((wave * 2) * 1024 + lane * 16);
  unsigned wdst = (unsigned)((wave * 4) * 1024 + lane * 16);

  auto STAGE = [&](unsigned bsel, int ks) {
    gload16(px[0] + ks * 64, smem + bsel * 8192 + xdst);
    gload16(px[1] + ks * 64, smem + bsel * 8192 + xdst + 1024);
    #pragma unroll
    for (int it = 0; it < 4; ++it) {
      gload16(p1[it] + ks * 128, smem + 16384 + bsel * 16384 + wdst + it * 1024);
      gload16(p3[it] + ks * 128, smem + 49152 + bsel * 16384 + wdst + it * 1024);
    }
  };

  STAGE(0, 0);
  unsigned buf = 0;
  for (int ks = 0; ks < 32; ++ks) {
    if (ks < 31) {
      STAGE(buf ^ 1u, ks + 1);
      asm volatile("s_waitcnt vmcnt(10)" ::: "memory");
    } else {
      asm volatile("s_waitcnt vmcnt(0)" ::: "memory");
    }
    __builtin_amdgcn_s_barrier();              // buf tile fully written, all waves
    unsigned xb = buf * 8192;
    unsigned w1b = 16384 + buf * 16384;
    unsigned w3b = 49152 + buf * 16384;
    bf16x8 af[4], b1f[4], b3f[4];
    #pragma unroll
    for (int mi = 0; mi < 4; ++mi)
      af[mi] = *(const bf16x8*)(smem + xb + offA[mi]);
    #pragma unroll
    for (int ni = 0; ni < 4; ++ni) {
      b1f[ni] = cvt8(*(const f32x4*)(smem + w1b + offB[ni][0]),
                     *(const f32x4*)(smem + w1b + offB[ni][1]));
      b3f[ni] = cvt8(*(const f32x4*)(smem + w3b + offB[ni][0]),
                     *(const f32x4*)(smem + w3b + offB[ni][1]));
    }
    #pragma unroll
    for (int ni = 0; ni < 4; ++ni)
      #pragma unroll
      for (int mi = 0; mi < 4; ++mi) {
        acc1[mi][ni] = __builtin_amdgcn_mfma_f32_16x16x32_bf16(af[mi], b1f[ni], acc1[mi][ni], 0, 0, 0);
        acc3[mi][ni] = __builtin_amdgcn_mfma_f32_16x16x32_bf16(af[mi], b3f[ni], acc3[mi][ni], 0, 0, 0);
      }
    __builtin_amdgcn_s_barrier();              // reads done before buf is overwritten
    buf ^= 1u;
  }

  #pragma unroll
  for (int mi = 0; mi < 4; ++mi) {
    int mb = wm * 64 + mi * 16 + lq * 4;
    #pragma unroll
    for (int r = 0; r < 4; ++r) {
      int lrow = mt * 128 + mb + r;
      if (lrow < Ne) {
        size_t hrow = (size_t)(rbase + lrow) * F_DIM;
        #pragma unroll
        for (int ni = 0; ni < 4; ++ni) {
          int f = nt * 128 + wn * 64 + ni * 16 + lr16;
          float a1v = acc1[mi][ni][r];
          float a3v = acc3[mi][ni][r];
          float hv = (a1v / (1.f + __expf(-a1v))) * a3v;
          H[hrow + f] = f2bf(hv);
        }
      }
    }
  }
}

// ---------------- GEMM2: Y = H @ w2^T (bf16 out), same counted pipeline (8 loads/step)
__global__ __launch_bounds__(256, 2) void moe_gemm2(
    const unsigned short* __restrict__ H, const float* __restrict__ w2s,
    const int* __restrict__ cnt, const int* __restrict__ rowbase,
    unsigned short* __restrict__ Ybf)
{
  int e = blockIdx.z, mt = blockIdx.y, nt = blockIdx.x;
  int Ne = cnt[e];
  if (mt * 128 >= Ne) return;
  int rbase = rowbase[e];

  __shared__ char smem[65536];

  int tid = threadIdx.x, lane = tid & 63, wave = tid >> 6;

  const char* pa[4];
  #pragma unroll
  for (int it = 0; it < 4; ++it) {
    int r = (wave * 4 + it) * 8 + (lane >> 3);
    int c = (lane & 7) ^ (r & 7);
    int grow = mt * 128 + r; if (grow >= Ne) grow = Ne - 1;
    pa[it] = (const char*)(H + (size_t)(rbase + grow) * F_DIM) + c * 16;
  }
  const float* w2e = w2s + (size_t)e * D_DIM * F_DIM + (size_t)(nt * 64) * F_DIM;
  const char* pb[4];
  #pragma unroll
  for (int it = 0; it < 4; ++it) {
    int r = (wave * 4 + it) * 4 + (lane >> 4);
    int c = (lane & 15) ^ (r & 7);
    pb[it] = (const char*)(w2e + (size_t)r * F_DIM) + c * 16;
  }

  int wm = wave >> 1, wn = wave & 1;
  int lr16 = lane & 15, lq = lane >> 4;

  f32x4 acc[4][2];
  #pragma unroll
  for (int i = 0; i < 4; ++i) { acc[i][0] = {0.f,0.f,0.f,0.f}; acc[i][1] = {0.f,0.f,0.f,0.f}; }

  unsigned dst = (unsigned)((wave * 4) * 1024 + lane * 16);

  auto STAGE = [&](unsigned bsel, int ks) {
    #pragma unroll
    for (int it = 0; it < 4; ++it) {
      gload16(pa[it] + ks * 128, smem + bsel * 16384 + dst + it * 1024);
      gload16(pb[it] + ks * 256, smem + 32768 + bsel * 16384 + dst + it * 1024);
    }
  };

  STAGE(0, 0);
  unsigned buf = 0;
  for (int ks = 0; ks < 64; ++ks) {
    if (ks < 63) {
      STAGE(buf ^ 1u, ks + 1);
      asm volatile("s_waitcnt vmcnt(8)" ::: "memory");
    } else {
      asm volatile("s_waitcnt vmcnt(0)" ::: "memory");
    }
    __builtin_amdgcn_s_barrier();
    unsigned ab = buf * 16384;
    unsigned bb = 32768 + buf * 16384;
    #pragma unroll
    for (int ksub = 0; ksub < 2; ++ksub) {
      bf16x8 af[4], bf[2];
      #pragma unroll
      for (int mi = 0; mi < 4; ++mi) {
        int m = wm * 64 + mi * 16 + lr16;
        unsigned off = (unsigned)(m * 128 + (((ksub * 4 + lq) ^ (m & 7)) * 16));
        af[mi] = *(const bf16x8*)(smem + ab + off);
      }
      #pragma unroll
      for (int ni = 0; ni < 2; ++ni) {
        int n = wn * 32 + ni * 16 + lr16;
        unsigned o0 = (unsigned)(n * 256 + (((ksub * 8 + lq * 2 + 0) ^ (n & 7)) * 16));
        unsigned o1 = (unsigned)(n * 256 + (((ksub * 8 + lq * 2 + 1) ^ (n & 7)) * 16));
        bf[ni] = cvt8(*(const f32x4*)(smem + bb + o0), *(const f32x4*)(smem + bb + o1));
      }
      #pragma unroll
      for (int mi = 0; mi < 4; ++mi)
        #pragma unroll
        for (int ni = 0; ni < 2; ++ni)
          acc[mi][ni] = __builtin_amdgcn_mfma_f32_16x16x32_bf16(af[mi], bf[ni], acc[mi][ni], 0, 0, 0);
    }
    __builtin_amdgcn_s_barrier();
    buf ^= 1u;
  }

  #pragma unroll
  for (int mi = 0; mi < 4; ++mi) {
    int mb = wm * 64 + mi * 16 + lq * 4;
    #pragma unroll
    for (int r = 0; r < 4; ++r) {
      int lrow = mt * 128 + mb + r;
      if (lrow < Ne) {
        size_t yrow = (size_t)(rbase + lrow) * D_DIM;
        #pragma unroll
        for (int ni = 0; ni < 2; ++ni) {
          int d = nt * 64 + wn * 32 + ni * 16 + lr16;
          Ybf[yrow + d] = f2bf(acc[mi][ni][r]);
        }
      }
    }
  }
}

// ---------------- combine
__global__ __launch_bounds__(128) void moe_combine(
    const unsigned short* __restrict__ Ybf, const int* __restrict__ rowpos,
    const float* __restrict__ topw, float* __restrict__ out)
{
  int t = blockIdx.x, tid = threadIdx.x;   // 8 cols per thread
  int r0 = rowpos[t * 2], r1 = rowpos[t * 2 + 1];
  float p0 = topw[t * 2], p1 = topw[t * 2 + 1];
  uint4 a = ((const uint4*)(Ybf + (size_t)r0 * D_DIM))[tid];
  uint4 b = ((const uint4*)(Ybf + (size_t)r1 * D_DIM))[tid];
  float4 o0, o1;
  #define LO(u) __builtin_bit_cast(float, (unsigned)((u) << 16))
  #define HI(u) __builtin_bit_cast(float, (unsigned)((u) & 0xffff0000u))
  o0.x = p0 * LO(a.x) + p1 * LO(b.x);  o0.y = p0 * HI(a.x) + p1 * HI(b.x);
  o0.z = p0 * LO(a.y) + p1 * LO(b.y);  o0.w = p0 * HI(a.y) + p1 * HI(b.y);
  o1.x = p0 * LO(a.z) + p1 * LO(b.z);  o1.y = p0 * HI(a.z) + p1 * HI(b.z);
  o1.z = p0 * LO(a.w) + p1 * LO(b.w);  o1.w = p0 * HI(a.w) + p1 * HI(b.w);
  #undef LO
  #undef HI
  float4* orow = (float4*)(out + (size_t)t * D_DIM);
  orow[tid * 2]     = o0;
  orow[tid * 2 + 1] = o1;
}

extern "C" void kernel_launch(void* const* d_in, const int* in_sizes, int n_in,
                              void* d_out, int out_size, void* d_ws, size_t ws_size,
                              hipStream_t stream) {
  const float* x    = (const float*)d_in[0];
  const float* gate = (const float*)d_in[1];
  const float* w1   = (const float*)d_in[2];
  const float* w2   = (const float*)d_in[3];
  const float* w3   = (const float*)d_in[4];
  float* out    = (float*)d_out;
  float* logits = out + (size_t)T_NUM * D_DIM;

  char* ws = (char*)d_ws;
  int*   cnt     = (int*)(ws + 0);
  int*   rowbase = (int*)(ws + 64);
  int*   topi    = (int*)(ws + 1024);
  float* topw    = (float*)(ws + 1024 + 16384);
  int*   rowlist = (int*)(ws + 1024 + 32768);
  int*   rowpos  = (int*)(ws + 1024 + 49152);
  unsigned short* H   = (unsigned short*)(ws + 131072);                      // 32 MB
  unsigned short* Ybf = (unsigned short*)(ws + 131072 + 33554432);           // 8 MB
  unsigned short* xbf = (unsigned short*)(ws + 131072 + 33554432 + 8388608); // 4 MB

  moe_xcast<<<(T_NUM * D_DIM) / (256 * 8), 256, 0, stream>>>(x, xbf);
  moe_router<<<T_NUM / 16, 256, 0, stream>>>(x, gate, logits, topi, topw);
  moe_route_build<<<1, 1024, 0, stream>>>(topi, cnt, rowbase, rowlist, rowpos);
  moe_gemm1<<<dim3(F_DIM / 128, T_NUM / 128, E_NUM), 256, 0, stream>>>(xbf, w1, w3, cnt, rowbase, rowlist, H);
  moe_gemm2<<<dim3(D_DIM / 64, T_NUM / 128, E_NUM), 256, 0, stream>>>(H, w2, cnt, rowbase, Ybf);
  moe_combine<<<T_NUM, 128, 0, stream>>>(Ybf, rowpos, topw, out);
}